// Round 3
// baseline (574.789 us; speedup 1.0000x reference)
//
#include <hip/hip_runtime.h>

// Anchor3DHead fused 1x1-conv heads, R5: 1 px/lane + deep explicit x-prefetch.
// R3/R4 post-mortem: any 2-px/lane (36-acc) body gets rewritten by the compiler
// into two single-pixel passes (VGPR_Count=32, FETCH +25..70%, time = R2) even
// with an 85-VGPR budget. Abandon that fight. R2's 18-acc body compiles clean
// (VGPR=20) but is latency-bound (VALUBusy 47%): loads are consumed in the same
// unroll body they're issued in. R5 keeps 18 accs/wave and adds a 2-deep
// rotating prefetch (CH=8 channels/buffer): each x-load is issued ~576 FMA-cyc
// before first use. asm "memory" fences pin the prefetch issue points so the
// scheduler cannot sink the loads back to their uses.
// Block = 256 threads = 4 waves; block covers 64 pixels (lane = pixel).
// Wave w owns 18 of 72 output channels over all 384 input channels:
//   w0: cls[0..18)  w1: reg[0..18)  w2: reg[18..36)  w3: reg[36..42)+dir[0..12)
// All 4 waves read the same x rows -> L1 dedupes to one HBM/L2 stream per block.

constexpr int Bn   = 4;
constexpr int Cc   = 384;
constexpr int Hh   = 248;
constexpr int Ww   = 216;
constexpr int HW   = Hh * Ww;          // 53568
constexpr int NPIX = Bn * HW;          // 214272 = 64 * 3348
constexpr int NCLS = 18;
constexpr int NREG = 42;
constexpr int NDIR = 12;
constexpr int CH   = 8;                // channels per prefetch buffer

// One wave's work: NA outputs from wA (row stride LDA) + NB outputs from wB
// (stride LDB), one pixel per lane. Weight addresses are wave-uniform ->
// scalar loads. x: one coalesced dword per lane per channel, prefetched two
// CH-chunks ahead (2*CH*N_ACC FMA-cycles of cover per load).
template<int NA, int LDA, int NB, int LDB>
__device__ __forceinline__ void cohort_run(
    const float* __restrict__ xb,
    const float* __restrict__ wA, const float* __restrict__ bA,
    float* __restrict__ oA,
    const float* __restrict__ wB, const float* __restrict__ bB,
    float* __restrict__ oB)
{
    constexpr int NO = NA + NB;
    float acc[NO];
    #pragma unroll
    for (int j = 0; j < NA; ++j) acc[j] = bA[j];
    #pragma unroll
    for (int j = 0; j < NB; ++j) acc[NA + j] = bB[j];

    // two rotating prefetch buffers: bufA holds chunk k, bufB chunk k+1
    float bufA[CH], bufB[CH];
    #pragma unroll
    for (int i = 0; i < CH; ++i) bufA[i] = xb[(size_t)i * HW];
    #pragma unroll
    for (int i = 0; i < CH; ++i) bufB[i] = xb[(size_t)(CH + i) * HW];

    for (int c0 = 0; c0 < Cc; c0 += 2 * CH) {   // 24 iterations
        // ---- half A: consume chunk c0 (bufA), prefetch chunk c0+2CH into bufA
        float xt[CH];
        #pragma unroll
        for (int i = 0; i < CH; ++i) xt[i] = bufA[i];
        if (c0 + 2 * CH < Cc) {
            #pragma unroll
            for (int i = 0; i < CH; ++i)
                bufA[i] = xb[(size_t)(c0 + 2 * CH + i) * HW];
        }
        asm volatile("" ::: "memory");   // pin prefetch issue point
        #pragma unroll
        for (int i = 0; i < CH; ++i) {
            const float* __restrict__ wra = wA + (size_t)(c0 + i) * LDA;
            const float* __restrict__ wrb = wB + (size_t)(c0 + i) * LDB;
            #pragma unroll
            for (int j = 0; j < NA; ++j) acc[j]      = fmaf(xt[i], wra[j], acc[j]);
            #pragma unroll
            for (int j = 0; j < NB; ++j) acc[NA + j] = fmaf(xt[i], wrb[j], acc[NA + j]);
        }

        // ---- half B: consume chunk c0+CH (bufB), prefetch c0+3CH into bufB
        #pragma unroll
        for (int i = 0; i < CH; ++i) xt[i] = bufB[i];
        if (c0 + 3 * CH < Cc) {
            #pragma unroll
            for (int i = 0; i < CH; ++i)
                bufB[i] = xb[(size_t)(c0 + 3 * CH + i) * HW];
        }
        asm volatile("" ::: "memory");
        #pragma unroll
        for (int i = 0; i < CH; ++i) {
            const float* __restrict__ wra = wA + (size_t)(c0 + CH + i) * LDA;
            const float* __restrict__ wrb = wB + (size_t)(c0 + CH + i) * LDB;
            #pragma unroll
            for (int j = 0; j < NA; ++j) acc[j]      = fmaf(xt[i], wra[j], acc[j]);
            #pragma unroll
            for (int j = 0; j < NB; ++j) acc[NA + j] = fmaf(xt[i], wrb[j], acc[NA + j]);
        }
    }

    // streamed outputs, never re-read: nontemporal to spare L2 for x
    #pragma unroll
    for (int j = 0; j < NA; ++j)
        __builtin_nontemporal_store(acc[j], oA + (size_t)j * HW);
    #pragma unroll
    for (int j = 0; j < NB; ++j)
        __builtin_nontemporal_store(acc[NA + j], oB + (size_t)j * HW);
}

__global__ __launch_bounds__(256, 6) void head_fused_pf(
    const float* __restrict__ x,
    const float* __restrict__ wc, const float* __restrict__ bc,
    const float* __restrict__ wr, const float* __restrict__ br,
    const float* __restrict__ wd, const float* __restrict__ bd,
    float* __restrict__ out)
{
    const int w    = threadIdx.x >> 6;       // wave id 0..3 (uniform per wave)
    const int lane = threadIdx.x & 63;
    const int pix  = blockIdx.x * 64 + lane; // < 214272 exactly
    const int b    = pix / HW;
    const int p    = pix - b * HW;

    const float* __restrict__ xb = x + (size_t)b * Cc * HW + p;

    float* __restrict__ outc = out + (size_t)b * NCLS * HW + p;
    float* __restrict__ outr = out + (size_t)Bn * NCLS * HW
                                   + (size_t)b * NREG * HW + p;
    float* __restrict__ outd = out + (size_t)Bn * (NCLS + NREG) * HW
                                   + (size_t)b * NDIR * HW + p;

    if (w == 0) {
        cohort_run<18, NCLS, 0, 1>(xb, wc, bc, outc, wc, bc, outc);
    } else if (w == 1) {
        cohort_run<18, NREG, 0, 1>(xb, wr, br, outr, wr, br, outr);
    } else if (w == 2) {
        cohort_run<18, NREG, 0, 1>(xb, wr + 18, br + 18, outr + (size_t)18 * HW,
                                   wr, br, outr);
    } else {
        cohort_run<6, NREG, 12, NDIR>(xb, wr + 36, br + 36, outr + (size_t)36 * HW,
                                      wd, bd, outd);
    }
}

extern "C" void kernel_launch(void* const* d_in, const int* in_sizes, int n_in,
                              void* d_out, int out_size, void* d_ws, size_t ws_size,
                              hipStream_t stream) {
    const float* x  = (const float*)d_in[0];
    const float* wc = (const float*)d_in[1];
    const float* bc = (const float*)d_in[2];
    const float* wr = (const float*)d_in[3];
    const float* br = (const float*)d_in[4];
    const float* wd = (const float*)d_in[5];
    const float* bd = (const float*)d_in[6];
    float* out = (float*)d_out;

    dim3 grid(NPIX / 64);    // 3348 blocks, exact cover (64 pixels per block)
    dim3 block(256);
    head_fused_pf<<<grid, block, 0, stream>>>(x, wc, bc, wr, br, wd, bd, out);
}